// Round 1
// baseline (660.025 us; speedup 1.0000x reference)
//
#include <hip/hip_runtime.h>
#include <hip/hip_bf16.h>
#include <stdint.h>

#define NN 100000
#define EE 1600000

// ---------------- edge dtype detect / normalize ----------------
__global__ void detect_kernel(const unsigned int* raw, int* flag) {
    int i = blockIdx.x * blockDim.x + threadIdx.x;
    if (i < 4096) {
        if (raw[2 * i + 1] != 0u) atomicOr(flag, 1);
    }
}

__global__ void convert_edges(const void* raw, const int* flag, int* src, int* dst, int E) {
    int e = blockIdx.x * blockDim.x + threadIdx.x;
    if (e >= E) return;
    if (*flag) { // int32 layout
        const int* p = (const int*)raw;
        src[e] = p[e];
        dst[e] = p[E + e];
    } else {     // int64 layout (hi words all zero)
        const long long* p = (const long long*)raw;
        src[e] = (int)p[e];
        dst[e] = (int)p[E + e];
    }
}

// ---------------- degree histogram ----------------
__global__ void hist_kernel(const int* dst, int* cnt, int E) {
    int e = blockIdx.x * blockDim.x + threadIdx.x;
    if (e < E) atomicAdd(&cnt[dst[e]], 1);
}

// ---------------- scan (3-phase) ----------------
#define SCAN_ELEMS 1024

__global__ void scan_block_sums(const int* cnt, int* blockSums, int n) {
    __shared__ int sdata[256];
    int t = threadIdx.x;
    int base = blockIdx.x * SCAN_ELEMS + t * 4;
    int s = 0;
    #pragma unroll
    for (int j = 0; j < 4; j++) { int i = base + j; if (i < n) s += cnt[i]; }
    sdata[t] = s; __syncthreads();
    for (int off = 128; off > 0; off >>= 1) {
        if (t < off) sdata[t] += sdata[t + off];
        __syncthreads();
    }
    if (t == 0) blockSums[blockIdx.x] = sdata[0];
}

__global__ void scan_top(const int* blockSums, int* blockPrefix, int nb, int* offsets, int N) {
    __shared__ int tmp[128];
    int t = threadIdx.x;
    int v = (t < nb) ? blockSums[t] : 0;
    tmp[t] = v; __syncthreads();
    for (int off = 1; off < 128; off <<= 1) {
        int add = (t >= off) ? tmp[t - off] : 0;
        __syncthreads();
        tmp[t] += add;
        __syncthreads();
    }
    if (t < nb) blockPrefix[t] = tmp[t] - v;        // exclusive
    if (t == 0) offsets[N] = tmp[127];              // grand total (= E)
}

__global__ void scan_write(const int* cnt, const int* blockPrefix, int* offsets, int n) {
    __shared__ int sdata[256];
    int t = threadIdx.x;
    int base = blockIdx.x * SCAN_ELEMS + t * 4;
    int v[4]; int s = 0;
    #pragma unroll
    for (int j = 0; j < 4; j++) { v[j] = (base + j < n) ? cnt[base + j] : 0; s += v[j]; }
    sdata[t] = s; __syncthreads();
    for (int off = 1; off < 256; off <<= 1) {
        int add = (t >= off) ? sdata[t - off] : 0;
        __syncthreads();
        sdata[t] += add;
        __syncthreads();
    }
    int run = sdata[t] - s + blockPrefix[blockIdx.x];
    #pragma unroll
    for (int j = 0; j < 4; j++) {
        if (base + j < n) { offsets[base + j] = run; run += v[j]; }
    }
}

// ---------------- bucket edges by dst ----------------
__global__ void bucket_kernel(const int* src, const int* dst, const int* offsets,
                              int* fill, int* srcs_sorted, int E) {
    int e = blockIdx.x * blockDim.x + threadIdx.x;
    if (e >= E) return;
    int d = dst[e];
    int pos = offsets[d] + atomicAdd(&fill[d], 1);
    srcs_sorted[pos] = src[e];
}

// ---------------- mean aggregation: one wave per node ----------------
template<int K>
__global__ void aggregate_kernel(const int* offsets, const int* srcs, const float* x,
                                 float* meanb, int N) {
    int wave = threadIdx.x >> 6;
    int lane = threadIdx.x & 63;
    int node = blockIdx.x * 4 + wave;   // blockDim = 256
    if (node >= N) return;
    int s0 = offsets[node], s1 = offsets[node + 1];
    float inv = 1.0f / fmaxf((float)(s1 - s0), 1.0f);
    if (K == 64) {
        float acc = 0.0f;
        for (int r = s0; r < s1; r++) {
            int s = srcs[r];
            acc += x[(size_t)s * 64 + lane];
        }
        meanb[(size_t)node * 64 + lane] = acc * inv;
    } else {
        float2 acc = make_float2(0.0f, 0.0f);
        for (int r = s0; r < s1; r++) {
            int s = srcs[r];
            float2 v = *(const float2*)&x[(size_t)s * 128 + 2 * lane];
            acc.x += v.x; acc.y += v.y;
        }
        float2 o = make_float2(acc.x * inv, acc.y * inv);
        *(float2*)&meanb[(size_t)node * 128 + 2 * lane] = o;
    }
}

// ---------------- fused SAGE linear: out = mean@Wl^T + bl + self@Wr^T ----------------
// Tile: 64 nodes x 128 outs per block of 256 threads; per-thread 4 nodes x 8 outs.
template<int K, bool RELU>   // K = per-matrix input dim (64 or 128); K_total = 2K
__global__ __launch_bounds__(256) void sage_gemm(const float* meanb, const float* selfx,
                                                 const float* Wl, const float* bl,
                                                 const float* Wr, float* out, int N) {
    __shared__ float Asub[64][33];
    __shared__ float Wsub[32][128];
    const int t = threadIdx.x;
    const int ox = t & 15;        // 16 groups of 8 outputs
    const int nz = t >> 4;        // 16 groups of 4 nodes
    const int o0 = ox * 8;
    const int nb = blockIdx.x * 64;
    const int n0 = nb + nz * 4;

    float acc[4][8];
    #pragma unroll
    for (int j = 0; j < 8; j++) {
        float b = bl[o0 + j];
        #pragma unroll
        for (int i = 0; i < 4; i++) acc[i][j] = b;
    }

    const int KT = 2 * K;
    for (int kk = 0; kk < KT; kk += 32) {
        const float* Amat = (kk < K) ? meanb : selfx;
        const float* Wmat = (kk < K) ? Wl : Wr;
        const int acol = (kk < K) ? kk : (kk - K);

        // stage A chunk: 64 rows x 32 cols  (512 float4 loads)
        #pragma unroll
        for (int l = 0; l < 2; l++) {
            int idx = t + l * 256;
            int r = idx >> 3, c4 = idx & 7;
            int n = nb + r;
            float4 v = make_float4(0.f, 0.f, 0.f, 0.f);
            if (n < N) v = *(const float4*)&Amat[(size_t)n * K + acol + c4 * 4];
            Asub[r][c4 * 4 + 0] = v.x;
            Asub[r][c4 * 4 + 1] = v.y;
            Asub[r][c4 * 4 + 2] = v.z;
            Asub[r][c4 * 4 + 3] = v.w;
        }
        // stage W chunk transposed: Wsub[k][o]
        {
            int o = t >> 1;
            int kbase = (t & 1) * 16;
            const float* wrow = &Wmat[(size_t)o * K + acol];
            #pragma unroll
            for (int j = 0; j < 16; j += 4) {
                float4 v = *(const float4*)&wrow[kbase + j];
                Wsub[kbase + j + 0][o] = v.x;
                Wsub[kbase + j + 1][o] = v.y;
                Wsub[kbase + j + 2][o] = v.z;
                Wsub[kbase + j + 3][o] = v.w;
            }
        }
        __syncthreads();

        #pragma unroll
        for (int k = 0; k < 32; k++) {
            float4 w0 = *(const float4*)&Wsub[k][o0];
            float4 w1 = *(const float4*)&Wsub[k][o0 + 4];
            float a[4];
            #pragma unroll
            for (int i = 0; i < 4; i++) a[i] = Asub[nz * 4 + i][k];
            #pragma unroll
            for (int i = 0; i < 4; i++) {
                acc[i][0] += a[i] * w0.x; acc[i][1] += a[i] * w0.y;
                acc[i][2] += a[i] * w0.z; acc[i][3] += a[i] * w0.w;
                acc[i][4] += a[i] * w1.x; acc[i][5] += a[i] * w1.y;
                acc[i][6] += a[i] * w1.z; acc[i][7] += a[i] * w1.w;
            }
        }
        __syncthreads();
    }

    #pragma unroll
    for (int i = 0; i < 4; i++) {
        int n = n0 + i;
        if (n >= N) continue;
        float4 r0 = make_float4(acc[i][0], acc[i][1], acc[i][2], acc[i][3]);
        float4 r1 = make_float4(acc[i][4], acc[i][5], acc[i][6], acc[i][7]);
        if (RELU) {
            r0.x = fmaxf(r0.x, 0.f); r0.y = fmaxf(r0.y, 0.f);
            r0.z = fmaxf(r0.z, 0.f); r0.w = fmaxf(r0.w, 0.f);
            r1.x = fmaxf(r1.x, 0.f); r1.y = fmaxf(r1.y, 0.f);
            r1.z = fmaxf(r1.z, 0.f); r1.w = fmaxf(r1.w, 0.f);
        }
        *(float4*)&out[(size_t)n * 128 + o0] = r0;
        *(float4*)&out[(size_t)n * 128 + o0 + 4] = r1;
    }
}

// ---------------- launch ----------------
extern "C" void kernel_launch(void* const* d_in, const int* in_sizes, int n_in,
                              void* d_out, int out_size, void* d_ws, size_t ws_size,
                              hipStream_t stream) {
    const float* x   = (const float*)d_in[0];
    const void*  er  = d_in[1];
    const float* Wl1 = (const float*)d_in[2];
    const float* bl1 = (const float*)d_in[3];
    const float* Wr1 = (const float*)d_in[4];
    const float* Wl2 = (const float*)d_in[5];
    const float* bl2 = (const float*)d_in[6];
    const float* Wr2 = (const float*)d_in[7];
    float* out = (float*)d_out;

    const int N = NN, E = EE;

    // workspace carve-up (512B aligned)
    char* ws = (char*)d_ws;
    size_t off = 0;
    auto carve = [&](size_t bytes) { char* p = ws + off; off += (bytes + 511) & ~(size_t)511; return p; };
    int*   flag      = (int*)  carve(4);
    int*   src32     = (int*)  carve((size_t)E * 4);
    int*   dst32     = (int*)  carve((size_t)E * 4);
    int*   fill      = (int*)  carve((size_t)N * 4);
    int*   offsets   = (int*)  carve((size_t)(N + 1) * 4);
    int*   blockSums = (int*)  carve(128 * 4);
    int*   blockPref = (int*)  carve(128 * 4);
    int*   srcs_sort = (int*)  carve((size_t)E * 4);
    float* meanbuf   = (float*)carve((size_t)N * 128 * 4);
    float* hbuf      = (float*)carve((size_t)N * 128 * 4);
    (void)ws_size;

    const int nb_scan = (N + SCAN_ELEMS - 1) / SCAN_ELEMS;   // 98
    const int eb = (E + 255) / 256;                          // 6250

    hipMemsetAsync(flag, 0, 4, stream);
    hipMemsetAsync(fill, 0, (size_t)N * 4, stream);

    detect_kernel<<<16, 256, 0, stream>>>((const unsigned int*)er, flag);
    convert_edges<<<eb, 256, 0, stream>>>(er, flag, src32, dst32, E);

    hist_kernel<<<eb, 256, 0, stream>>>(dst32, fill, E);     // fill := degree
    scan_block_sums<<<nb_scan, 256, 0, stream>>>(fill, blockSums, N);
    scan_top<<<1, 128, 0, stream>>>(blockSums, blockPref, nb_scan, offsets, N);
    scan_write<<<nb_scan, 256, 0, stream>>>(fill, blockPref, offsets, N);

    hipMemsetAsync(fill, 0, (size_t)N * 4, stream);
    bucket_kernel<<<eb, 256, 0, stream>>>(src32, dst32, offsets, fill, srcs_sort, E);

    const int ab = (N + 3) / 4;                              // 25000 (4 waves/block)
    const int gb = (N + 63) / 64;                            // 1563

    // layer 1
    aggregate_kernel<64><<<ab, 256, 0, stream>>>(offsets, srcs_sort, x, meanbuf, N);
    sage_gemm<64, true><<<gb, 256, 0, stream>>>(meanbuf, x, Wl1, bl1, Wr1, hbuf, N);

    // layer 2
    aggregate_kernel<128><<<ab, 256, 0, stream>>>(offsets, srcs_sort, hbuf, meanbuf, N);
    sage_gemm<128, false><<<gb, 256, 0, stream>>>(meanbuf, hbuf, Wl2, bl2, Wr2, out, N);
}

// Round 2
// 524.719 us; speedup vs baseline: 1.2579x; 1.2579x over previous
//
#include <hip/hip_runtime.h>
#include <hip/hip_bf16.h>
#include <stdint.h>

#define NN 100000
#define EE 1600000

// ---------------- edge dtype detect / normalize ----------------
__global__ void detect_kernel(const unsigned int* raw, int* flag) {
    int i = blockIdx.x * blockDim.x + threadIdx.x;
    if (i < 4096) {
        if (raw[2 * i + 1] != 0u) atomicOr(flag, 1);
    }
}

__global__ void convert_edges(const void* raw, const int* flag, int* src, int* dst, int E) {
    int e = blockIdx.x * blockDim.x + threadIdx.x;
    if (e >= E) return;
    if (*flag) { // int32 layout
        const int* p = (const int*)raw;
        src[e] = p[e];
        dst[e] = p[E + e];
    } else {     // int64 layout (hi words all zero)
        const long long* p = (const long long*)raw;
        src[e] = (int)p[e];
        dst[e] = (int)p[E + e];
    }
}

// ---------------- degree histogram ----------------
__global__ void hist_kernel(const int* dst, int* cnt, int E) {
    int e = blockIdx.x * blockDim.x + threadIdx.x;
    if (e < E) atomicAdd(&cnt[dst[e]], 1);
}

// ---------------- scan (3-phase) ----------------
#define SCAN_ELEMS 1024

__global__ void scan_block_sums(const int* cnt, int* blockSums, int n) {
    __shared__ int sdata[256];
    int t = threadIdx.x;
    int base = blockIdx.x * SCAN_ELEMS + t * 4;
    int s = 0;
    #pragma unroll
    for (int j = 0; j < 4; j++) { int i = base + j; if (i < n) s += cnt[i]; }
    sdata[t] = s; __syncthreads();
    for (int off = 128; off > 0; off >>= 1) {
        if (t < off) sdata[t] += sdata[t + off];
        __syncthreads();
    }
    if (t == 0) blockSums[blockIdx.x] = sdata[0];
}

__global__ void scan_top(const int* blockSums, int* blockPrefix, int nb, int* offsets, int N) {
    __shared__ int tmp[128];
    int t = threadIdx.x;
    int v = (t < nb) ? blockSums[t] : 0;
    tmp[t] = v; __syncthreads();
    for (int off = 1; off < 128; off <<= 1) {
        int add = (t >= off) ? tmp[t - off] : 0;
        __syncthreads();
        tmp[t] += add;
        __syncthreads();
    }
    if (t < nb) blockPrefix[t] = tmp[t] - v;        // exclusive
    if (t == 0) offsets[N] = tmp[127];              // grand total (= E)
}

__global__ void scan_write(const int* cnt, const int* blockPrefix, int* offsets, int n) {
    __shared__ int sdata[256];
    int t = threadIdx.x;
    int base = blockIdx.x * SCAN_ELEMS + t * 4;
    int v[4]; int s = 0;
    #pragma unroll
    for (int j = 0; j < 4; j++) { v[j] = (base + j < n) ? cnt[base + j] : 0; s += v[j]; }
    sdata[t] = s; __syncthreads();
    for (int off = 1; off < 256; off <<= 1) {
        int add = (t >= off) ? sdata[t - off] : 0;
        __syncthreads();
        sdata[t] += add;
        __syncthreads();
    }
    int run = sdata[t] - s + blockPrefix[blockIdx.x];
    #pragma unroll
    for (int j = 0; j < 4; j++) {
        if (base + j < n) { offsets[base + j] = run; run += v[j]; }
    }
}

// ---------------- bucket edges by dst ----------------
__global__ void bucket_kernel(const int* src, const int* dst, const int* offsets,
                              int* fill, int* srcs_sorted, int E) {
    int e = blockIdx.x * blockDim.x + threadIdx.x;
    if (e >= E) return;
    int d = dst[e];
    int pos = offsets[d] + atomicAdd(&fill[d], 1);
    srcs_sorted[pos] = src[e];
}

// ---------------- mean aggregation: one wave per node ----------------
// Lane-cooperative index load (srcs[base+lane] once per 64 edges, broadcast
// via __shfl) + 4-way unrolled gathers with 4 accumulators for MLP.
template<int K>
__global__ void aggregate_kernel(const int* offsets, const int* srcs, const float* x,
                                 float* meanb, int N) {
    int wave = threadIdx.x >> 6;
    int lane = threadIdx.x & 63;
    int node = blockIdx.x * 4 + wave;   // blockDim = 256
    if (node >= N) return;
    int s0 = offsets[node], s1 = offsets[node + 1];
    float inv = 1.0f / fmaxf((float)(s1 - s0), 1.0f);

    if (K == 64) {
        float a0 = 0.f, a1 = 0.f, a2 = 0.f, a3 = 0.f;
        for (int base = s0; base < s1; base += 64) {
            int cnt = min(64, s1 - base);
            int myidx = (base + lane < s1) ? srcs[base + lane] : 0;
            int j = 0;
            for (; j + 4 <= cnt; j += 4) {
                int sa = __shfl(myidx, j);
                int sb = __shfl(myidx, j + 1);
                int sc = __shfl(myidx, j + 2);
                int sd = __shfl(myidx, j + 3);
                float va = x[(size_t)sa * 64 + lane];
                float vb = x[(size_t)sb * 64 + lane];
                float vc = x[(size_t)sc * 64 + lane];
                float vd = x[(size_t)sd * 64 + lane];
                a0 += va; a1 += vb; a2 += vc; a3 += vd;
            }
            for (; j < cnt; j++) {
                int s = __shfl(myidx, j);
                a0 += x[(size_t)s * 64 + lane];
            }
        }
        meanb[(size_t)node * 64 + lane] = (a0 + a1 + a2 + a3) * inv;
    } else {
        float2 a0 = make_float2(0.f, 0.f), a1 = make_float2(0.f, 0.f);
        float2 a2 = make_float2(0.f, 0.f), a3 = make_float2(0.f, 0.f);
        for (int base = s0; base < s1; base += 64) {
            int cnt = min(64, s1 - base);
            int myidx = (base + lane < s1) ? srcs[base + lane] : 0;
            int j = 0;
            for (; j + 4 <= cnt; j += 4) {
                int sa = __shfl(myidx, j);
                int sb = __shfl(myidx, j + 1);
                int sc = __shfl(myidx, j + 2);
                int sd = __shfl(myidx, j + 3);
                float2 va = *(const float2*)&x[(size_t)sa * 128 + 2 * lane];
                float2 vb = *(const float2*)&x[(size_t)sb * 128 + 2 * lane];
                float2 vc = *(const float2*)&x[(size_t)sc * 128 + 2 * lane];
                float2 vd = *(const float2*)&x[(size_t)sd * 128 + 2 * lane];
                a0.x += va.x; a0.y += va.y;
                a1.x += vb.x; a1.y += vb.y;
                a2.x += vc.x; a2.y += vc.y;
                a3.x += vd.x; a3.y += vd.y;
            }
            for (; j < cnt; j++) {
                int s = __shfl(myidx, j);
                float2 v = *(const float2*)&x[(size_t)s * 128 + 2 * lane];
                a0.x += v.x; a0.y += v.y;
            }
        }
        float2 o = make_float2((a0.x + a1.x + a2.x + a3.x) * inv,
                               (a0.y + a1.y + a2.y + a3.y) * inv);
        *(float2*)&meanb[(size_t)node * 128 + 2 * lane] = o;
    }
}

// ---------------- fused SAGE linear: out = mean@Wl^T + bl + self@Wr^T ----------------
// Tile: 64 nodes x 128 outs per block of 256 threads; per-thread 4 nodes x 8 outs.
template<int K, bool RELU>   // K = per-matrix input dim (64 or 128); K_total = 2K
__global__ __launch_bounds__(256) void sage_gemm(const float* meanb, const float* selfx,
                                                 const float* Wl, const float* bl,
                                                 const float* Wr, float* out, int N) {
    __shared__ float Asub[64][33];
    __shared__ float Wsub[32][128];
    const int t = threadIdx.x;
    const int ox = t & 15;        // 16 groups of 8 outputs
    const int nz = t >> 4;        // 16 groups of 4 nodes
    const int o0 = ox * 8;
    const int nb = blockIdx.x * 64;
    const int n0 = nb + nz * 4;

    float acc[4][8];
    #pragma unroll
    for (int j = 0; j < 8; j++) {
        float b = bl[o0 + j];
        #pragma unroll
        for (int i = 0; i < 4; i++) acc[i][j] = b;
    }

    const int KT = 2 * K;
    for (int kk = 0; kk < KT; kk += 32) {
        const float* Amat = (kk < K) ? meanb : selfx;
        const float* Wmat = (kk < K) ? Wl : Wr;
        const int acol = (kk < K) ? kk : (kk - K);

        // stage A chunk: 64 rows x 32 cols  (512 float4 loads)
        #pragma unroll
        for (int l = 0; l < 2; l++) {
            int idx = t + l * 256;
            int r = idx >> 3, c4 = idx & 7;
            int n = nb + r;
            float4 v = make_float4(0.f, 0.f, 0.f, 0.f);
            if (n < N) v = *(const float4*)&Amat[(size_t)n * K + acol + c4 * 4];
            Asub[r][c4 * 4 + 0] = v.x;
            Asub[r][c4 * 4 + 1] = v.y;
            Asub[r][c4 * 4 + 2] = v.z;
            Asub[r][c4 * 4 + 3] = v.w;
        }
        // stage W chunk transposed: Wsub[k][o]
        {
            int o = t >> 1;
            int kbase = (t & 1) * 16;
            const float* wrow = &Wmat[(size_t)o * K + acol];
            #pragma unroll
            for (int j = 0; j < 16; j += 4) {
                float4 v = *(const float4*)&wrow[kbase + j];
                Wsub[kbase + j + 0][o] = v.x;
                Wsub[kbase + j + 1][o] = v.y;
                Wsub[kbase + j + 2][o] = v.z;
                Wsub[kbase + j + 3][o] = v.w;
            }
        }
        __syncthreads();

        #pragma unroll
        for (int k = 0; k < 32; k++) {
            float4 w0 = *(const float4*)&Wsub[k][o0];
            float4 w1 = *(const float4*)&Wsub[k][o0 + 4];
            float a[4];
            #pragma unroll
            for (int i = 0; i < 4; i++) a[i] = Asub[nz * 4 + i][k];
            #pragma unroll
            for (int i = 0; i < 4; i++) {
                acc[i][0] += a[i] * w0.x; acc[i][1] += a[i] * w0.y;
                acc[i][2] += a[i] * w0.z; acc[i][3] += a[i] * w0.w;
                acc[i][4] += a[i] * w1.x; acc[i][5] += a[i] * w1.y;
                acc[i][6] += a[i] * w1.z; acc[i][7] += a[i] * w1.w;
            }
        }
        __syncthreads();
    }

    #pragma unroll
    for (int i = 0; i < 4; i++) {
        int n = n0 + i;
        if (n >= N) continue;
        float4 r0 = make_float4(acc[i][0], acc[i][1], acc[i][2], acc[i][3]);
        float4 r1 = make_float4(acc[i][4], acc[i][5], acc[i][6], acc[i][7]);
        if (RELU) {
            r0.x = fmaxf(r0.x, 0.f); r0.y = fmaxf(r0.y, 0.f);
            r0.z = fmaxf(r0.z, 0.f); r0.w = fmaxf(r0.w, 0.f);
            r1.x = fmaxf(r1.x, 0.f); r1.y = fmaxf(r1.y, 0.f);
            r1.z = fmaxf(r1.z, 0.f); r1.w = fmaxf(r1.w, 0.f);
        }
        *(float4*)&out[(size_t)n * 128 + o0] = r0;
        *(float4*)&out[(size_t)n * 128 + o0 + 4] = r1;
    }
}

// ---------------- launch ----------------
extern "C" void kernel_launch(void* const* d_in, const int* in_sizes, int n_in,
                              void* d_out, int out_size, void* d_ws, size_t ws_size,
                              hipStream_t stream) {
    const float* x   = (const float*)d_in[0];
    const void*  er  = d_in[1];
    const float* Wl1 = (const float*)d_in[2];
    const float* bl1 = (const float*)d_in[3];
    const float* Wr1 = (const float*)d_in[4];
    const float* Wl2 = (const float*)d_in[5];
    const float* bl2 = (const float*)d_in[6];
    const float* Wr2 = (const float*)d_in[7];
    float* out = (float*)d_out;

    const int N = NN, E = EE;

    // workspace carve-up (512B aligned)
    char* ws = (char*)d_ws;
    size_t off = 0;
    auto carve = [&](size_t bytes) { char* p = ws + off; off += (bytes + 511) & ~(size_t)511; return p; };
    int*   flag      = (int*)  carve(4);
    int*   src32     = (int*)  carve((size_t)E * 4);
    int*   dst32     = (int*)  carve((size_t)E * 4);
    int*   fill      = (int*)  carve((size_t)N * 4);
    int*   offsets   = (int*)  carve((size_t)(N + 1) * 4);
    int*   blockSums = (int*)  carve(128 * 4);
    int*   blockPref = (int*)  carve(128 * 4);
    int*   srcs_sort = (int*)  carve((size_t)E * 4);
    float* meanbuf   = (float*)carve((size_t)N * 128 * 4);
    float* hbuf      = (float*)carve((size_t)N * 128 * 4);
    (void)ws_size;

    const int nb_scan = (N + SCAN_ELEMS - 1) / SCAN_ELEMS;   // 98
    const int eb = (E + 255) / 256;                          // 6250

    hipMemsetAsync(flag, 0, 4, stream);
    hipMemsetAsync(fill, 0, (size_t)N * 4, stream);

    detect_kernel<<<16, 256, 0, stream>>>((const unsigned int*)er, flag);
    convert_edges<<<eb, 256, 0, stream>>>(er, flag, src32, dst32, E);

    hist_kernel<<<eb, 256, 0, stream>>>(dst32, fill, E);     // fill := degree
    scan_block_sums<<<nb_scan, 256, 0, stream>>>(fill, blockSums, N);
    scan_top<<<1, 128, 0, stream>>>(blockSums, blockPref, nb_scan, offsets, N);
    scan_write<<<nb_scan, 256, 0, stream>>>(fill, blockPref, offsets, N);

    hipMemsetAsync(fill, 0, (size_t)N * 4, stream);
    bucket_kernel<<<eb, 256, 0, stream>>>(src32, dst32, offsets, fill, srcs_sort, E);

    const int ab = (N + 3) / 4;                              // 25000 (4 waves/block)
    const int gb = (N + 63) / 64;                            // 1563

    // layer 1
    aggregate_kernel<64><<<ab, 256, 0, stream>>>(offsets, srcs_sort, x, meanbuf, N);
    sage_gemm<64, true><<<gb, 256, 0, stream>>>(meanbuf, x, Wl1, bl1, Wr1, hbuf, N);

    // layer 2
    aggregate_kernel<128><<<ab, 256, 0, stream>>>(offsets, srcs_sort, hbuf, meanbuf, N);
    sage_gemm<128, false><<<gb, 256, 0, stream>>>(meanbuf, hbuf, Wl2, bl2, Wr2, out, N);
}

// Round 3
// 413.077 us; speedup vs baseline: 1.5978x; 1.2703x over previous
//
#include <hip/hip_runtime.h>
#include <hip/hip_bf16.h>
#include <stdint.h>

#define NN 100000
#define EE 1600000

typedef __attribute__((ext_vector_type(4))) float f32x4;
typedef __attribute__((ext_vector_type(8))) short bf16x8;

__device__ inline ushort f2bf(float f) {
    union { float f; uint32_t u; } v; v.f = f;
    uint32_t u = v.u;
    uint32_t r = (u + 0x7fffu + ((u >> 16) & 1u)) >> 16;   // RNE
    return (ushort)r;
}
__device__ inline float bf2f(ushort h) {
    union { uint32_t u; float f; } v; v.u = ((uint32_t)h) << 16; return v.f;
}
__device__ inline float bflo(uint32_t u) {
    union { uint32_t u; float f; } v; v.u = u << 16; return v.f;
}
__device__ inline float bfhi(uint32_t u) {
    union { uint32_t u; float f; } v; v.u = u & 0xffff0000u; return v.f;
}

// ---------------- edge dtype detect / normalize ----------------
__global__ void detect_kernel(const unsigned int* raw, int* flag) {
    int i = blockIdx.x * blockDim.x + threadIdx.x;
    if (i < 4096) {
        if (raw[2 * i + 1] != 0u) atomicOr(flag, 1);
    }
}

__global__ void convert_edges(const void* raw, const int* flag, int* src, int* dst, int E) {
    int e = blockIdx.x * blockDim.x + threadIdx.x;
    if (e >= E) return;
    if (*flag) { // int32 layout
        const int* p = (const int*)raw;
        src[e] = p[e];
        dst[e] = p[E + e];
    } else {     // int64 layout (hi words all zero)
        const long long* p = (const long long*)raw;
        src[e] = (int)p[e];
        dst[e] = (int)p[E + e];
    }
}

// ---------------- dtype conversion passes ----------------
__global__ void cvt_f32_bf16(const float* __restrict__ in, ushort* __restrict__ out, int n4) {
    int i = blockIdx.x * blockDim.x + threadIdx.x;   // one float4 per thread
    if (i >= n4) return;
    float4 v = *(const float4*)&in[i * 4];
    ushort o[4] = { f2bf(v.x), f2bf(v.y), f2bf(v.z), f2bf(v.w) };
    *(uint64_t*)&out[i * 4] = *(const uint64_t*)o;
}

// Wcat[o][0..K) = Wl[o][:], Wcat[o][K..2K) = Wr[o][:]  (bf16)
__global__ void build_wcat(const float* __restrict__ Wl, const float* __restrict__ Wr,
                           ushort* __restrict__ Wcat, int K) {
    int t = blockIdx.x * blockDim.x + threadIdx.x;
    int KT = 2 * K;
    if (t >= 128 * KT) return;
    int o = t / KT, k = t % KT;
    float v = (k < K) ? Wl[o * K + k] : Wr[o * K + (k - K)];
    Wcat[o * KT + k] = f2bf(v);
}

// ---------------- degree histogram ----------------
__global__ void hist_kernel(const int* dst, int* cnt, int E) {
    int e = blockIdx.x * blockDim.x + threadIdx.x;
    if (e < E) atomicAdd(&cnt[dst[e]], 1);
}

// ---------------- scan (3-phase) ----------------
#define SCAN_ELEMS 1024

__global__ void scan_block_sums(const int* cnt, int* blockSums, int n) {
    __shared__ int sdata[256];
    int t = threadIdx.x;
    int base = blockIdx.x * SCAN_ELEMS + t * 4;
    int s = 0;
    #pragma unroll
    for (int j = 0; j < 4; j++) { int i = base + j; if (i < n) s += cnt[i]; }
    sdata[t] = s; __syncthreads();
    for (int off = 128; off > 0; off >>= 1) {
        if (t < off) sdata[t] += sdata[t + off];
        __syncthreads();
    }
    if (t == 0) blockSums[blockIdx.x] = sdata[0];
}

__global__ void scan_top(const int* blockSums, int* blockPrefix, int nb, int* offsets, int N) {
    __shared__ int tmp[128];
    int t = threadIdx.x;
    int v = (t < nb) ? blockSums[t] : 0;
    tmp[t] = v; __syncthreads();
    for (int off = 1; off < 128; off <<= 1) {
        int add = (t >= off) ? tmp[t - off] : 0;
        __syncthreads();
        tmp[t] += add;
        __syncthreads();
    }
    if (t < nb) blockPrefix[t] = tmp[t] - v;        // exclusive
    if (t == 0) offsets[N] = tmp[127];              // grand total (= E)
}

__global__ void scan_write(const int* cnt, const int* blockPrefix, int* offsets, int n) {
    __shared__ int sdata[256];
    int t = threadIdx.x;
    int base = blockIdx.x * SCAN_ELEMS + t * 4;
    int v[4]; int s = 0;
    #pragma unroll
    for (int j = 0; j < 4; j++) { v[j] = (base + j < n) ? cnt[base + j] : 0; s += v[j]; }
    sdata[t] = s; __syncthreads();
    for (int off = 1; off < 256; off <<= 1) {
        int add = (t >= off) ? sdata[t - off] : 0;
        __syncthreads();
        sdata[t] += add;
        __syncthreads();
    }
    int run = sdata[t] - s + blockPrefix[blockIdx.x];
    #pragma unroll
    for (int j = 0; j < 4; j++) {
        if (base + j < n) { offsets[base + j] = run; run += v[j]; }
    }
}

// ---------------- bucket edges by dst ----------------
__global__ void bucket_kernel(const int* src, const int* dst, const int* offsets,
                              int* fill, int* srcs_sorted, int E) {
    int e = blockIdx.x * blockDim.x + threadIdx.x;
    if (e >= E) return;
    int d = dst[e];
    int pos = offsets[d] + atomicAdd(&fill[d], 1);
    srcs_sorted[pos] = src[e];
}

// ---------------- mean aggregation (bf16 in, bf16 out): one wave per node ----------------
template<int K>
__global__ void aggregate_kernel(const int* __restrict__ offsets, const int* __restrict__ srcs,
                                 const ushort* __restrict__ xb, ushort* __restrict__ meanb, int N) {
    int wave = threadIdx.x >> 6;
    int lane = threadIdx.x & 63;
    int node = blockIdx.x * 4 + wave;   // blockDim = 256
    if (node >= N) return;
    int s0 = offsets[node], s1 = offsets[node + 1];
    float inv = 1.0f / fmaxf((float)(s1 - s0), 1.0f);

    if (K == 64) {
        float a0 = 0.f, a1 = 0.f, a2 = 0.f, a3 = 0.f;
        for (int base = s0; base < s1; base += 64) {
            int cnt = min(64, s1 - base);
            int myidx = (base + lane < s1) ? srcs[base + lane] : 0;
            int j = 0;
            for (; j + 4 <= cnt; j += 4) {
                int sa = __shfl(myidx, j);
                int sb = __shfl(myidx, j + 1);
                int sc = __shfl(myidx, j + 2);
                int sd = __shfl(myidx, j + 3);
                float va = bf2f(xb[(size_t)sa * 64 + lane]);
                float vb = bf2f(xb[(size_t)sb * 64 + lane]);
                float vc = bf2f(xb[(size_t)sc * 64 + lane]);
                float vd = bf2f(xb[(size_t)sd * 64 + lane]);
                a0 += va; a1 += vb; a2 += vc; a3 += vd;
            }
            for (; j < cnt; j++) {
                int s = __shfl(myidx, j);
                a0 += bf2f(xb[(size_t)s * 64 + lane]);
            }
        }
        meanb[(size_t)node * 64 + lane] = f2bf((a0 + a1 + a2 + a3) * inv);
    } else {
        float x0 = 0.f, y0 = 0.f, x1 = 0.f, y1 = 0.f;
        float x2 = 0.f, y2 = 0.f, x3 = 0.f, y3 = 0.f;
        for (int base = s0; base < s1; base += 64) {
            int cnt = min(64, s1 - base);
            int myidx = (base + lane < s1) ? srcs[base + lane] : 0;
            int j = 0;
            for (; j + 4 <= cnt; j += 4) {
                int sa = __shfl(myidx, j);
                int sb = __shfl(myidx, j + 1);
                int sc = __shfl(myidx, j + 2);
                int sd = __shfl(myidx, j + 3);
                uint32_t ua = *(const uint32_t*)&xb[(size_t)sa * 128 + 2 * lane];
                uint32_t ub = *(const uint32_t*)&xb[(size_t)sb * 128 + 2 * lane];
                uint32_t uc = *(const uint32_t*)&xb[(size_t)sc * 128 + 2 * lane];
                uint32_t ud = *(const uint32_t*)&xb[(size_t)sd * 128 + 2 * lane];
                x0 += bflo(ua); y0 += bfhi(ua);
                x1 += bflo(ub); y1 += bfhi(ub);
                x2 += bflo(uc); y2 += bfhi(uc);
                x3 += bflo(ud); y3 += bfhi(ud);
            }
            for (; j < cnt; j++) {
                int s = __shfl(myidx, j);
                uint32_t u = *(const uint32_t*)&xb[(size_t)s * 128 + 2 * lane];
                x0 += bflo(u); y0 += bfhi(u);
            }
        }
        ushort o[2] = { f2bf((x0 + x1 + x2 + x3) * inv), f2bf((y0 + y1 + y2 + y3) * inv) };
        *(uint32_t*)&meanb[(size_t)node * 128 + 2 * lane] = *(const uint32_t*)o;
    }
}

// ---------------- MFMA SAGE linear: out = [mean|self] @ Wcat^T + bl ----------------
// Block: 256 threads = 4 waves; wave owns 32 rows x 128 cols. No LDS, no syncs.
// Fragment layout (16x16x32 bf16): A row = lane&15, k = (lane>>4)*8+j;
// B col = lane&15, same k; C col = lane&15, row = (lane>>4)*4+reg.
template<int K, bool RELU, bool OUT_BF16>
__global__ __launch_bounds__(256) void sage_gemm_mfma(
    const ushort* __restrict__ meanb, const ushort* __restrict__ selfb,
    const ushort* __restrict__ Wcat, const float* __restrict__ bl,
    void* __restrict__ outv, int N)
{
    const int KT = 2 * K;
    const int wave = threadIdx.x >> 6;
    const int lane = threadIdx.x & 63;
    const int lrow = lane & 15;
    const int lgrp = lane >> 4;
    const int n0 = blockIdx.x * 128 + wave * 32;

    f32x4 acc[2][8];
    #pragma unroll
    for (int h = 0; h < 2; h++)
        #pragma unroll
        for (int t = 0; t < 8; t++)
            acc[h][t] = (f32x4){0.f, 0.f, 0.f, 0.f};

    const int ar0 = min(n0 + lrow, N - 1);
    const int ar1 = min(n0 + 16 + lrow, N - 1);

    #pragma unroll
    for (int ks = 0; ks < KT; ks += 32) {
        const ushort* Ap = (ks < K) ? meanb : selfb;
        const int ac = (ks < K) ? ks : (ks - K);
        bf16x8 a0 = *(const bf16x8*)&Ap[(size_t)ar0 * K + ac + lgrp * 8];
        bf16x8 a1 = *(const bf16x8*)&Ap[(size_t)ar1 * K + ac + lgrp * 8];
        #pragma unroll
        for (int t = 0; t < 8; t++) {
            bf16x8 b = *(const bf16x8*)&Wcat[(size_t)(t * 16 + lrow) * KT + ks + lgrp * 8];
            acc[0][t] = __builtin_amdgcn_mfma_f32_16x16x32_bf16(a0, b, acc[0][t], 0, 0, 0);
            acc[1][t] = __builtin_amdgcn_mfma_f32_16x16x32_bf16(a1, b, acc[1][t], 0, 0, 0);
        }
    }

    #pragma unroll
    for (int t = 0; t < 8; t++) {
        int c = t * 16 + lrow;
        float bias = bl[c];
        #pragma unroll
        for (int h = 0; h < 2; h++) {
            #pragma unroll
            for (int r = 0; r < 4; r++) {
                int n = n0 + h * 16 + lgrp * 4 + r;
                if (n < N) {
                    float v = acc[h][t][r] + bias;
                    if (RELU) v = fmaxf(v, 0.0f);
                    if (OUT_BF16) ((ushort*)outv)[(size_t)n * 128 + c] = f2bf(v);
                    else         ((float*)outv)[(size_t)n * 128 + c] = v;
                }
            }
        }
    }
}

// ---------------- launch ----------------
extern "C" void kernel_launch(void* const* d_in, const int* in_sizes, int n_in,
                              void* d_out, int out_size, void* d_ws, size_t ws_size,
                              hipStream_t stream) {
    const float* x   = (const float*)d_in[0];
    const void*  er  = d_in[1];
    const float* Wl1 = (const float*)d_in[2];
    const float* bl1 = (const float*)d_in[3];
    const float* Wr1 = (const float*)d_in[4];
    const float* Wl2 = (const float*)d_in[5];
    const float* bl2 = (const float*)d_in[6];
    const float* Wr2 = (const float*)d_in[7];
    float* out = (float*)d_out;

    const int N = NN, E = EE;

    // workspace carve-up (512B aligned)
    char* ws = (char*)d_ws;
    size_t off = 0;
    auto carve = [&](size_t bytes) { char* p = ws + off; off += (bytes + 511) & ~(size_t)511; return p; };
    int*    flag      = (int*)   carve(4);
    int*    src32     = (int*)   carve((size_t)E * 4);
    int*    dst32     = (int*)   carve((size_t)E * 4);
    int*    fill      = (int*)   carve((size_t)N * 4);
    int*    offsets   = (int*)   carve((size_t)(N + 1) * 4);
    int*    blockSums = (int*)   carve(128 * 4);
    int*    blockPref = (int*)   carve(128 * 4);
    int*    srcs_sort = (int*)   carve((size_t)E * 4);
    ushort* xb        = (ushort*)carve((size_t)N * 64 * 2);
    ushort* meanb     = (ushort*)carve((size_t)N * 128 * 2);
    ushort* hb        = (ushort*)carve((size_t)N * 128 * 2);
    ushort* wc1       = (ushort*)carve((size_t)128 * 128 * 2);
    ushort* wc2       = (ushort*)carve((size_t)128 * 256 * 2);
    (void)ws_size;

    const int nb_scan = (N + SCAN_ELEMS - 1) / SCAN_ELEMS;   // 98
    const int eb = (E + 255) / 256;                          // 6250

    hipMemsetAsync(flag, 0, 4, stream);
    hipMemsetAsync(fill, 0, (size_t)N * 4, stream);

    detect_kernel<<<16, 256, 0, stream>>>((const unsigned int*)er, flag);
    convert_edges<<<eb, 256, 0, stream>>>(er, flag, src32, dst32, E);

    // bf16 conversions (independent of CSR build)
    cvt_f32_bf16<<<(N * 64 / 4 + 255) / 256, 256, 0, stream>>>(x, xb, N * 64 / 4);
    build_wcat<<<(128 * 128 + 255) / 256, 256, 0, stream>>>(Wl1, Wr1, wc1, 64);
    build_wcat<<<(128 * 256 + 255) / 256, 256, 0, stream>>>(Wl2, Wr2, wc2, 128);

    hist_kernel<<<eb, 256, 0, stream>>>(dst32, fill, E);     // fill := degree
    scan_block_sums<<<nb_scan, 256, 0, stream>>>(fill, blockSums, N);
    scan_top<<<1, 128, 0, stream>>>(blockSums, blockPref, nb_scan, offsets, N);
    scan_write<<<nb_scan, 256, 0, stream>>>(fill, blockPref, offsets, N);

    hipMemsetAsync(fill, 0, (size_t)N * 4, stream);
    bucket_kernel<<<eb, 256, 0, stream>>>(src32, dst32, offsets, fill, srcs_sort, E);

    const int ab = (N + 3) / 4;                              // 25000 (4 waves/block)
    const int gb = (N + 127) / 128;                          // 782

    // layer 1
    aggregate_kernel<64><<<ab, 256, 0, stream>>>(offsets, srcs_sort, xb, meanb, N);
    sage_gemm_mfma<64, true, true><<<gb, 256, 0, stream>>>(meanb, xb, wc1, bl1, hb, N);

    // layer 2
    aggregate_kernel<128><<<ab, 256, 0, stream>>>(offsets, srcs_sort, hb, meanb, N);
    sage_gemm_mfma<128, false, false><<<gb, 256, 0, stream>>>(meanb, hb, wc2, bl2, out, N);
}